// Round 3
// baseline (4197.775 us; speedup 1.0000x reference)
//
#include <hip/hip_runtime.h>

// 2-layer LSTM encoder, fused single kernel, v7: register-resident state +
// readlane-broadcast dots; minimal sync structure.
//
// ROUND-2 POST-MORTEM: v6 cut aggregate LDS b128 reads ~4x but only gained
// 130 cyc/step (1460->1330). Conclusion: step time = slowest-wave issue
// (~300cy) + ~1000cy FIXED overhead = 8-wave barrier + ds_write->lgkm->
// barrier->ds_read visibility round trip + dep-chain latency. VALUBusy 20%.
//
// v7 attacks the fixed part:
//  * h-state lives in REGISTERS distributed lane=unit; dot products consume
//    it via v_readlane SGPR broadcast (VALU pipe, ~4cy dep; no LDS).
//  * L1 = 2 waves, 32 units each; lane pair (2j,2j+1) = unit; even lane
//    computes gates (i,f), odd (g,o), full K=68 (136 weight VGPRs).
//    (i,f)<->(g,o) exchange = 1 intra-wave DPP quad_perm swap. c,h kept
//    redundantly in both lanes of the pair.
//  * L2 = 1 wave, lane pair = unit, 2 gates x K=96 (192 weight VGPRs);
//    h2 never leaves registers (readlane(h2reg, 2k)).
//  * Only cross-wave traffic: 64 floats h1/step: even L1 lanes ds_write_b32
//    -> lgkmcnt(0) -> 3-wave s_barrier -> all lanes ds_read_b32 (parity
//    double-buffered). One barrier/step, width 3 waves (was 8).
//  * x via uniform prefetch (1 load/step, latency hidden); xbuf ring gone.
//
// Schedule: 64 blocks (1/batch), 192 threads = 3 waves -> 1 wave/SIMD;
// amdgpu_waves_per_eu(1,1) => 256-VGPR budget so weights stay resident.
// Iteration n: L1 computes h1(n) [n<T]; L2 computes h2(t=n-1) [n>=1] from
// h1(n-1) (register copy read at end of iter n-1) and h2(n-2) (h2reg).

#define BATCH 64
#define T 4096
#define NTHREADS 192
#define L2E 1.442695040888963f

__device__ __forceinline__ float fast_rcp(float v) { return __builtin_amdgcn_rcpf(v); }

__device__ __forceinline__ float bcast_lane(float v, int k) {
    return __int_as_float(__builtin_amdgcn_readlane(__float_as_int(v), k));
}

// quad_perm [1,0,3,2]: swap lanes within each (even,odd) pair. Full-rate VALU.
__device__ __forceinline__ float dpp_qxor1(float v) {
    return __int_as_float(__builtin_amdgcn_update_dpp(0, __float_as_int(v), 0xB1, 0xF, 0xF, true));
}

// Barrier without the vmcnt(0) drain __syncthreads would emit.
#define LDS_BARRIER() do {                                   \
    asm volatile("s_waitcnt lgkmcnt(0)" ::: "memory");       \
    __builtin_amdgcn_s_barrier();                            \
    asm volatile("" ::: "memory");                           \
} while (0)

__global__ __launch_bounds__(NTHREADS)
__attribute__((amdgpu_waves_per_eu(1, 1)))
void lstm2_fused_v7(const float* __restrict__ x,
                    const float* __restrict__ W_ih1, const float* __restrict__ W_hh1,
                    const float* __restrict__ b_ih1, const float* __restrict__ b_hh1,
                    const float* __restrict__ W_ih2, const float* __restrict__ W_hh2,
                    const float* __restrict__ b_ih2, const float* __restrict__ b_hh2,
                    float* __restrict__ out)
{
    const int b    = blockIdx.x;
    const int tid  = threadIdx.x;
    const int wave = tid >> 6;
    const int lane = tid & 63;
    const bool is_l1 = (wave < 2);
    const int pair = lane >> 1;        // unit within wave
    const int odd  = lane & 1;         // 0: gates (i,f); 1: gates (g,o)

    __shared__ float h1buf[2][64];     // parity ring for h1 publish

    // ---- per-lane weights in registers (all indices compile-time) ----
    float wA[96], wB[96];              // L1 uses [0..67]; L2 [0..95]
    float biasA, biasB;
    float h1reg = 0.0f;                // lane l holds h1(n-1)[l]
    float h2reg = 0.0f;                // lanes 2u,2u+1 hold h2[u]
    float c = 0.0f;

    if (is_l1) {
        const int unit = (wave << 5) + pair;          // 0..63
        const int rA = ((odd ? 2 : 0) << 6) + unit;   // gate rows in [256]
        const int rB = ((odd ? 3 : 1) << 6) + unit;
#pragma unroll
        for (int k = 0; k < 64; ++k) {
            wA[k] = W_hh1[(size_t)rA * 64 + k];
            wB[k] = W_hh1[(size_t)rB * 64 + k];
        }
#pragma unroll
        for (int j = 0; j < 4; ++j) {
            wA[64 + j] = W_ih1[rA * 4 + j];
            wB[64 + j] = W_ih1[rB * 4 + j];
        }
        biasA = b_ih1[rA] + b_hh1[rA];
        biasB = b_ih1[rB] + b_hh1[rB];
    } else {
        const int unit = pair;                        // 0..31
        const int rA = ((odd ? 2 : 0) << 5) + unit;   // gate rows in [128]
        const int rB = ((odd ? 3 : 1) << 5) + unit;
#pragma unroll
        for (int k = 0; k < 64; ++k) {
            wA[k] = W_ih2[(size_t)rA * 64 + k];
            wB[k] = W_ih2[(size_t)rB * 64 + k];
        }
#pragma unroll
        for (int k = 0; k < 32; ++k) {
            wA[64 + k] = W_hh2[(size_t)rA * 32 + k];
            wB[64 + k] = W_hh2[(size_t)rB * 32 + k];
        }
        biasA = b_ih2[rA] + b_hh2[rA];
        biasB = b_ih2[rB] + b_hh2[rB];
    }

    // gate A activation: even = sigmoid(i), odd = tanh(g); gate B always sigmoid.
    const float scA_in  = odd ? -2.0f * L2E : -L2E;
    const float scA_out = odd ?  2.0f : 1.0f;
    const float scA_off = odd ? -1.0f : 0.0f;

    const float* xb   = x + (size_t)b * T * 4;
    float*       outb = out + (size_t)b * T * 32;
    float4 xv = *(const float4*)xb;    // x(0)

    for (int n = 0; n <= T; ++n) {
        const int cur = n & 1;
        // prefetch x(n+1): uniform address, latency hidden across the step
        float4 xnx = xv;
        if (n + 1 < T) xnx = *(const float4*)(xb + (size_t)(n + 1) * 4);

        if (is_l1) {
            if (n < T) {
                float aA = biasA, aB = biasB;
#pragma unroll
                for (int k = 0; k < 64; ++k) {
                    const float hk = bcast_lane(h1reg, k);
                    aA = fmaf(hk, wA[k], aA);
                    aB = fmaf(hk, wB[k], aB);
                }
                aA = fmaf(xv.x, wA[64], aA); aB = fmaf(xv.x, wB[64], aB);
                aA = fmaf(xv.y, wA[65], aA); aB = fmaf(xv.y, wB[65], aB);
                aA = fmaf(xv.z, wA[66], aA); aB = fmaf(xv.z, wB[66], aB);
                aA = fmaf(xv.w, wA[67], aA); aB = fmaf(xv.w, wB[67], aB);
                const float actA = fmaf(scA_out, fast_rcp(1.0f + exp2f(scA_in * aA)), scA_off);
                const float actB = fast_rcp(1.0f + exp2f(-L2E * aB));
                const float pA = dpp_qxor1(actA);   // partner's A
                const float pB = dpp_qxor1(actB);   // partner's B
                const float gi = odd ? pA : actA;
                const float gf = odd ? pB : actB;
                const float gg = odd ? actA : pA;
                const float go = odd ? actB : pB;
                c = fmaf(gf, c, gi * gg);
                const float th = fmaf(-2.0f, fast_rcp(exp2f(2.0f * L2E * c) + 1.0f), 1.0f);
                const float h = go * th;
                if (!odd) h1buf[cur][(wave << 5) + pair] = h;
            }
        } else {
            if (n >= 1) {
                float aA = biasA, aB = biasB;
#pragma unroll
                for (int k = 0; k < 64; ++k) {
                    const float hk = bcast_lane(h1reg, k);    // h1(n-1)[k]
                    aA = fmaf(hk, wA[k], aA);
                    aB = fmaf(hk, wB[k], aB);
                }
#pragma unroll
                for (int k = 0; k < 32; ++k) {
                    const float hk = bcast_lane(h2reg, 2 * k); // h2(n-2)[k]
                    aA = fmaf(hk, wA[64 + k], aA);
                    aB = fmaf(hk, wB[64 + k], aB);
                }
                const float actA = fmaf(scA_out, fast_rcp(1.0f + exp2f(scA_in * aA)), scA_off);
                const float actB = fast_rcp(1.0f + exp2f(-L2E * aB));
                const float pA = dpp_qxor1(actA);
                const float pB = dpp_qxor1(actB);
                const float gi = odd ? pA : actA;
                const float gf = odd ? pB : actB;
                const float gg = odd ? actA : pA;
                const float go = odd ? actB : pB;
                c = fmaf(gf, c, gi * gg);
                const float th = fmaf(-2.0f, fast_rcp(exp2f(2.0f * L2E * c) + 1.0f), 1.0f);
                const float h = go * th;
                h2reg = h;                                   // both pair lanes hold h2[u]
                if (!odd) outb[(size_t)(n - 1) * 32 + pair] = h;
            }
        }

        LDS_BARRIER();
        if (n < T) h1reg = h1buf[cur][lane];   // h1(n) -> register, all 3 waves
        xv = xnx;
    }
}

extern "C" void kernel_launch(void* const* d_in, const int* in_sizes, int n_in,
                              void* d_out, int out_size, void* d_ws, size_t ws_size,
                              hipStream_t stream) {
    const float* x     = (const float*)d_in[0];
    const float* W_ih1 = (const float*)d_in[1];
    const float* W_hh1 = (const float*)d_in[2];
    const float* b_ih1 = (const float*)d_in[3];
    const float* b_hh1 = (const float*)d_in[4];
    const float* W_ih2 = (const float*)d_in[5];
    const float* W_hh2 = (const float*)d_in[6];
    const float* b_ih2 = (const float*)d_in[7];
    const float* b_hh2 = (const float*)d_in[8];
    float* out = (float*)d_out;

    lstm2_fused_v7<<<dim3(BATCH), dim3(NTHREADS), 0, stream>>>(
        x, W_ih1, W_hh1, b_ih1, b_hh1, W_ih2, W_hh2, b_ih2, b_hh2, out);
}

// Round 5
// 2286.854 us; speedup vs baseline: 1.8356x; 1.8356x over previous
//
#include <hip/hip_runtime.h>

// 2-layer LSTM encoder, fused single kernel, v8b = v8 with the LOADG2
// preprocessor fix (round-4 failure: `w##G##0.x` pastes against the
// pp-number token `0.x` -> invalid token `w00.x`; build via make_float4).
//
// ROUND-3 POST-MORTEM: v7's weight arrays (float wA[96]) were runtime-indexed
// at SROA time (SROA runs before unroll) -> allocated in SCRATCH, reloaded
// every step (VGPR=132 << 210 needed; FETCH 2601->4618 KB). v6 had the same
// disease (w[4][17], hh[17]; VGPR stuck at 88 == v5). The "fixed 1000-cyc
// sync overhead" theorized in round 2 was actually per-step scratch reload
// (~160 KB/step/CU from L1/L2 ~ 600-800 cyc). v5 was immune: named float4s.
//
// v8 = v6's verified math/schedule (K-split dots, DPP butterflies, concat
// hbuf[96], lgkm-only barrier, 2-chunk x ring, 512 thr / 8 waves,
// waves_per_eu(2,2)) with zero private arrays:
//   L1 lane (waves 0-3): unit = 16*wave + lane>>2, kq = lane&3. Per gate g:
//     w{g}0..w{g}3 (float4, W_hh1 K-quarter), wx{g} (W_ih1), bi{g}.
//     17 FMAs/gate into p{g}; quad butterfly (xor1,xor2) -> full sums.
//   L2 lane (waves 4-7): unit = 8*(wave-4) + lane>>3, m8 = lane&7. Per gate:
//     w{g}0..w{g}2 (float4, 12-elem slice of concat [W_ih2(64)|W_hh2(32)]).
//     12 FMAs/gate; butterfly xor1,xor2 + xor4 (row_shl/shr4 + select).
//   Ring parity: iter n reads hbuf[(n+1)&1] (h1(n-1),h2(n-2)), writes
//   hbuf[n&1]; loop unrolled x2; tail STEP(T) finishes h2(T-1).

#define BATCH 64
#define T 4096
#define NTHREADS 512
#define L2E 1.442695040888963f

__device__ __forceinline__ float fast_rcp(float v) { return __builtin_amdgcn_rcpf(v); }

// DPP cross-lane helpers (full-rate VALU, no LDS pipe).
__device__ __forceinline__ float dpp_qxor1(float v) {   // quad_perm [1,0,3,2]
    return __int_as_float(__builtin_amdgcn_update_dpp(0, __float_as_int(v), 0xB1, 0xF, 0xF, true));
}
__device__ __forceinline__ float dpp_qxor2(float v) {   // quad_perm [2,3,0,1]
    return __int_as_float(__builtin_amdgcn_update_dpp(0, __float_as_int(v), 0x4E, 0xF, 0xF, true));
}
__device__ __forceinline__ float dpp_shl4(float v) {    // lane i <- lane i+4
    return __int_as_float(__builtin_amdgcn_update_dpp(0, __float_as_int(v), 0x104, 0xF, 0xF, true));
}
__device__ __forceinline__ float dpp_shr4(float v) {    // lane i <- lane i-4
    return __int_as_float(__builtin_amdgcn_update_dpp(0, __float_as_int(v), 0x114, 0xF, 0xF, true));
}

// Barrier without the vmcnt(0) drain __syncthreads would emit.
#define LDS_BARRIER() do {                                   \
    asm volatile("s_waitcnt lgkmcnt(0)" ::: "memory");       \
    __builtin_amdgcn_s_barrier();                            \
    asm volatile("" ::: "memory");                           \
} while (0)

#define SIGM(v) fast_rcp(1.0f + exp2f(-L2E * (v)))

__global__ __launch_bounds__(NTHREADS)
__attribute__((amdgpu_waves_per_eu(2, 2)))
void lstm2_fused_v8b(const float* __restrict__ x,
                     const float* __restrict__ W_ih1, const float* __restrict__ W_hh1,
                     const float* __restrict__ b_ih1, const float* __restrict__ b_hh1,
                     const float* __restrict__ W_ih2, const float* __restrict__ W_hh2,
                     const float* __restrict__ b_ih2, const float* __restrict__ b_hh2,
                     float* __restrict__ out)
{
    const int b    = blockIdx.x;
    const int tid  = threadIdx.x;
    const int wave = tid >> 6;
    const int lane = tid & 63;
    const bool is_l1 = (wave < 4);
    const int kq = lane & 3;     // L1 K-quarter
    const int m8 = lane & 7;     // L2 K-octet (12-elem slice index)

    __shared__ __align__(16) float hbuf[2][96];      // [ring][0..63]=h1, [64..95]=h2
    __shared__ __align__(16) float xbuf[2][64][4];   // 2-chunk x ring

    if (tid < 192) ((float*)hbuf)[tid] = 0.0f;

    // ---- per-lane weights: NAMED registers only (no private arrays!) ----
    float4 w00, w01, w02, w03;   // gate 0 (i)
    float4 w10, w11, w12, w13;   // gate 1 (f)
    float4 w20, w21, w22, w23;   // gate 2 (g)
    float4 w30, w31, w32, w33;   // gate 3 (o)
    float  wx0, wx1, wx2, wx3;   // L1: W_ih1[r*4+kq]
    float  bi0, bi1, bi2, bi3;
    float  c = 0.0f;
    int    uidx;

    if (is_l1) {
        uidx = (wave << 4) + (lane >> 2);            // unit 0..63
#define LOADG1(G) do {                                                          \
        const int r = ((G) << 6) + uidx;                                        \
        const float4* row = (const float4*)(W_hh1 + (size_t)r * 64 + (kq << 4));\
        w##G##0 = row[0]; w##G##1 = row[1]; w##G##2 = row[2]; w##G##3 = row[3]; \
        wx##G = W_ih1[r * 4 + kq];                                              \
        bi##G = (kq == 0) ? (b_ih1[r] + b_hh1[r]) : 0.0f;                       \
    } while (0)
        LOADG1(0); LOADG1(1); LOADG1(2); LOADG1(3);
#undef LOADG1
    } else {
        uidx = ((wave - 4) << 3) + (lane >> 3);      // unit 0..31
        const int k0 = 12 * m8;                      // slice start in concat [96]
#define CATW(r, kk) ((kk) < 64 ? W_ih2[(size_t)(r) * 64 + (kk)]                 \
                               : W_hh2[(size_t)(r) * 32 + ((kk) - 64)])
#define LOADG2(G) do {                                                          \
        const int r = ((G) << 5) + uidx;                                        \
        w##G##0 = make_float4(CATW(r, k0 + 0),  CATW(r, k0 + 1),                \
                              CATW(r, k0 + 2),  CATW(r, k0 + 3));               \
        w##G##1 = make_float4(CATW(r, k0 + 4),  CATW(r, k0 + 5),                \
                              CATW(r, k0 + 6),  CATW(r, k0 + 7));               \
        w##G##2 = make_float4(CATW(r, k0 + 8),  CATW(r, k0 + 9),                \
                              CATW(r, k0 + 10), CATW(r, k0 + 11));              \
        w##G##3 = make_float4(0.f, 0.f, 0.f, 0.f);                              \
        wx##G = 0.0f;                                                           \
        bi##G = (m8 == 0) ? (b_ih2[r] + b_hh2[r]) : 0.0f;                       \
    } while (0)
        LOADG2(0); LOADG2(1); LOADG2(2); LOADG2(3);
#undef LOADG2
#undef CATW
    }

    const float4* xptr = (const float4*)(x + (size_t)b * T * 4);
    float4 xg = make_float4(0.f, 0.f, 0.f, 0.f);
    if (wave == 0) {
        float4 x0 = xptr[lane];                      // chunk 0
        *(float4*)&xbuf[0][lane][0] = x0;
        xg = xptr[64 + lane];                        // chunk 1 in flight
    }
    float* outb = out + (size_t)b * T * 32;

    __syncthreads();                                  // full barrier once

#define FMA4(W, HH, P) do { P = fmaf((HH).x, (W).x, P); P = fmaf((HH).y, (W).y, P); \
                            P = fmaf((HH).z, (W).z, P); P = fmaf((HH).w, (W).w, P); } while (0)

#define STEP(nn, cur, prv)                                                        \
  do {                                                                            \
    if (is_l1) {                                                                  \
      if ((nn) < T) {                                                             \
        const int s = (nn) & 63;                                                  \
        if (s == 0 && wave == 0) {                                                \
            const int cch = (nn) >> 6;                                            \
            *(float4*)&xbuf[(cch + 1) & 1][lane][0] = xg;                         \
            const int nb = (cch + 2) << 6;                                        \
            if (nb < T) xg = xptr[nb + lane];                                     \
        }                                                                         \
        const float4* hv = (const float4*)&hbuf[prv][kq << 4];                    \
        const float4 ha = hv[0], hb = hv[1], hc = hv[2], hd = hv[3];              \
        const float xs = xbuf[((nn) >> 6) & 1][s][kq];                            \
        float p0 = bi0, p1 = bi1, p2 = bi2, p3 = bi3;                             \
        FMA4(w00, ha, p0); FMA4(w10, ha, p1); FMA4(w20, ha, p2); FMA4(w30, ha, p3); \
        FMA4(w01, hb, p0); FMA4(w11, hb, p1); FMA4(w21, hb, p2); FMA4(w31, hb, p3); \
        FMA4(w02, hc, p0); FMA4(w12, hc, p1); FMA4(w22, hc, p2); FMA4(w32, hc, p3); \
        FMA4(w03, hd, p0); FMA4(w13, hd, p1); FMA4(w23, hd, p2); FMA4(w33, hd, p3); \
        p0 = fmaf(xs, wx0, p0); p1 = fmaf(xs, wx1, p1);                           \
        p2 = fmaf(xs, wx2, p2); p3 = fmaf(xs, wx3, p3);                           \
        p0 += dpp_qxor1(p0); p1 += dpp_qxor1(p1);                                 \
        p2 += dpp_qxor1(p2); p3 += dpp_qxor1(p3);                                 \
        p0 += dpp_qxor2(p0); p1 += dpp_qxor2(p1);                                 \
        p2 += dpp_qxor2(p2); p3 += dpp_qxor2(p3);                                 \
        const float gi = SIGM(p0);                                                \
        const float gf = SIGM(p1);                                                \
        const float gg = fmaf(2.0f, fast_rcp(1.0f + exp2f(-2.0f * L2E * p2)), -1.0f); \
        const float go = SIGM(p3);                                                \
        c = fmaf(gf, c, gi * gg);                                                 \
        const float th = fmaf(-2.0f, fast_rcp(exp2f(2.0f * L2E * c) + 1.0f), 1.0f); \
        const float h = go * th;                                                  \
        if (kq == 0) hbuf[cur][uidx] = h;                                         \
      }                                                                           \
    } else {                                                                      \
      if ((nn) >= 1) {                                                            \
        const float* hp = &hbuf[prv][m8 * 12];       /* concat [h1|h2] slice */   \
        const float4 ca = *(const float4*)(hp + 0);                              \
        const float4 cb = *(const float4*)(hp + 4);                              \
        const float4 cc = *(const float4*)(hp + 8);                              \
        float p0 = bi0, p1 = bi1, p2 = bi2, p3 = bi3;                             \
        FMA4(w00, ca, p0); FMA4(w10, ca, p1); FMA4(w20, ca, p2); FMA4(w30, ca, p3); \
        FMA4(w01, cb, p0); FMA4(w11, cb, p1); FMA4(w21, cb, p2); FMA4(w31, cb, p3); \
        FMA4(w02, cc, p0); FMA4(w12, cc, p1); FMA4(w22, cc, p2); FMA4(w32, cc, p3); \
        p0 += dpp_qxor1(p0); p1 += dpp_qxor1(p1);                                 \
        p2 += dpp_qxor1(p2); p3 += dpp_qxor1(p3);                                 \
        p0 += dpp_qxor2(p0); p1 += dpp_qxor2(p1);                                 \
        p2 += dpp_qxor2(p2); p3 += dpp_qxor2(p3);                                 \
        {                                                                         \
          const float u0 = dpp_shl4(p0), d0 = dpp_shr4(p0);                       \
          const float u1 = dpp_shl4(p1), d1 = dpp_shr4(p1);                       \
          const float u2 = dpp_shl4(p2), d2 = dpp_shr4(p2);                       \
          const float u3 = dpp_shl4(p3), d3 = dpp_shr4(p3);                       \
          p0 += (lane & 4) ? d0 : u0;                                             \
          p1 += (lane & 4) ? d1 : u1;                                             \
          p2 += (lane & 4) ? d2 : u2;                                             \
          p3 += (lane & 4) ? d3 : u3;                                             \
        }                                                                         \
        const float gi = SIGM(p0);                                                \
        const float gf = SIGM(p1);                                                \
        const float gg = fmaf(2.0f, fast_rcp(1.0f + exp2f(-2.0f * L2E * p2)), -1.0f); \
        const float go = SIGM(p3);                                                \
        c = fmaf(gf, c, gi * gg);                                                 \
        const float th = fmaf(-2.0f, fast_rcp(exp2f(2.0f * L2E * c) + 1.0f), 1.0f); \
        const float h = go * th;                                                  \
        if (m8 == 0) {                                                            \
            hbuf[cur][64 + uidx] = h;                                             \
            outb[(size_t)((nn) - 1) * 32 + uidx] = h;                             \
        }                                                                         \
      }                                                                           \
    }                                                                             \
    LDS_BARRIER();                                                                \
  } while (0)

    for (int n = 0; n < T; n += 2) {
        STEP(n, 0, 1);
        STEP(n + 1, 1, 0);
    }
    STEP(T, 0, 1);       // final L2 step (computes t = T-1); L1 side folds away

#undef STEP
#undef FMA4
}

extern "C" void kernel_launch(void* const* d_in, const int* in_sizes, int n_in,
                              void* d_out, int out_size, void* d_ws, size_t ws_size,
                              hipStream_t stream) {
    const float* x     = (const float*)d_in[0];
    const float* W_ih1 = (const float*)d_in[1];
    const float* W_hh1 = (const float*)d_in[2];
    const float* b_ih1 = (const float*)d_in[3];
    const float* b_hh1 = (const float*)d_in[4];
    const float* W_ih2 = (const float*)d_in[5];
    const float* W_hh2 = (const float*)d_in[6];
    const float* b_ih2 = (const float*)d_in[7];
    const float* b_hh2 = (const float*)d_in[8];
    float* out = (float*)d_out;

    lstm2_fused_v8b<<<dim3(BATCH), dim3(NTHREADS), 0, stream>>>(
        x, W_ih1, W_hh1, b_ih1, b_hh1, W_ih2, W_hh2, b_ih2, b_hh2, out);
}